// Round 1
// baseline (1531.060 us; speedup 1.0000x reference)
//
#include <hip/hip_runtime.h>

// APPNP propagation - ROUND 15: feature-chunked gather (2 x 25 feats, 64-B rows).
// Theory: phase-7 gathers are bound by scattered 64-B line traffic to the
// Infinity Cache (~42 Glines/s): 12.8 MB plane vs 4 MB per-XCD L2 -> ~31% hit,
// 2.2M L3 lines/iter = 52 us. Features are independent across propagation, so
// split D=50 into two 25-feat chunks padded to 32 elems (64-B rows, 1 line per
// gather, same total line count). Per-chunk plane = 6.4 MB -> ~62% L2 hit ->
// L3 lines halve. Streams (col_idx, feat, plane stores) use non-temporal ops
// to keep L2 for the gather plane. Gather restructured to 8-lane-group dwordx2
// loads: 8 rows per wave-instruction, butterfly-reduced at the end (8x fewer
// VMEM+shfl instructions, 16 lines in flight per load).
//
// Math: feat_{k+1} = 0.9 * norm * (A_T (feat_k * norm)) + 0.1 * feat_0,
// norm = clip(indeg,1)^(-0.5), indeg over dst (d_in[1]=src, d_in[2]=dst).
//
// Buffers: two bf16 planes P0/P1 (100k x 32 elems = 6.4 MB each) in ws;
// per chunk c: g0 -> P0, it1 P0->P1, ..., it10 reads P1, writes fp32 cols
// c*25..c*25+24 of d_out. d_out is never scratch (no aliasing).
//
// Phases: 0 zero+probes | 1 indeg | 2 chunk sums | 3 scan | 4 rowptr+cursor
// +norm | 5 scatter col_idx | 6 g0(chunk) | 7 gather-propagate(chunk).

#define NN 100000
#define EE 1600000
#define DD 50
#define PS 32   // padded plane row stride (elems) = 64 B
#define CF 25   // features per chunk
#define KK 10
#define NBLK 391

__device__ __forceinline__ float feat_at(const void* f, long long i, int ft) {
    if (ft) return ((const float*)f)[i];
    unsigned int w = ((unsigned int)((const unsigned short*)f)[i]) << 16;
    return __uint_as_float(w);
}

__device__ __forceinline__ float feat_nt(const void* f, long long i, int ft) {
    if (ft) return __builtin_nontemporal_load((const float*)f + i);
    unsigned int w = ((unsigned int)__builtin_nontemporal_load(
                         (const unsigned short*)f + i)) << 16;
    return __uint_as_float(w);
}

__device__ __forceinline__ unsigned short bf16_st(float x) {
    unsigned int u = __float_as_uint(x);
    unsigned int r = (u + 0x7FFF + ((u >> 16) & 1)) >> 16; // round-nearest-even
    return (unsigned short)r;
}

__global__ __launch_bounds__(512) void APPNPConv_62199716381208_kernel(
        const void* featp, const void* srcp, const void* dstp,
        int* deg, float* norm, int* row_ptr, int* col_idx, int* bsum, int* flag,
        const unsigned short* gin, unsigned short* gout, float* outp,
        int phase, int last, int chunk) {
    __shared__ int sh[512];
    const int tid = threadIdx.x;
    const int gidx = blockIdx.x * blockDim.x + tid;

    if (phase == 0) {
        if (gidx < NN) deg[gidx] = 0;
        if (blockIdx.x == 0 && tid == 0) {
            const int* a = (const int*)dstp;
            int odd_or = a[1] | a[3] | a[5] | a[7] | a[9] | a[11] | a[13] | a[15];
            flag[0] = (odd_or == 0) ? 1 : 0;
            const unsigned short* w = (const unsigned short*)featp;
            int isf32 = 0;
            for (int k = 0; k < 64; ++k) {
                unsigned int b = ((unsigned int)w[k]) << 16;
                float ax = fabsf(__uint_as_float(b));
                if (!(ax < 100.0f)) isf32 = 1;
            }
            flag[1] = isf32;
        }
        return;
    }
    if (phase == 1) {
        if (gidx < EE) {
            int d = flag[0] ? (int)((const long long*)dstp)[gidx]
                            : ((const int*)dstp)[gidx];
            if ((unsigned int)d < (unsigned int)NN) atomicAdd(&deg[d], 1);
        }
        return;
    }
    if (phase == 2) {
        int i = blockIdx.x * 256 + tid;
        sh[tid] = (i < NN) ? deg[i] : 0;
        __syncthreads();
        for (int off = 128; off > 0; off >>= 1) {
            if (tid < off) sh[tid] += sh[tid + off];
            __syncthreads();
        }
        if (tid == 0) bsum[blockIdx.x] = sh[0];
        return;
    }
    if (phase == 3) {
        int v = (tid < NBLK) ? bsum[tid] : 0;
        sh[tid] = v;
        __syncthreads();
        for (int off = 1; off < 512; off <<= 1) {
            int x = (tid >= off) ? sh[tid - off] : 0;
            __syncthreads();
            sh[tid] += x;
            __syncthreads();
        }
        if (tid < NBLK) bsum[tid] = sh[tid] - v;
        return;
    }
    if (phase == 4) {
        int i = blockIdx.x * 256 + tid;
        int v = (i < NN) ? deg[i] : 0;
        sh[tid] = v;
        __syncthreads();
        for (int off = 1; off < 256; off <<= 1) {
            int x = (tid >= off) ? sh[tid - off] : 0;
            __syncthreads();
            sh[tid] += x;
            __syncthreads();
        }
        int excl = sh[tid] - v + bsum[blockIdx.x];
        if (i < NN) {
            row_ptr[i] = excl;
            deg[i] = excl; // becomes scatter cursor
            norm[i] = rsqrtf((float)(v < 1 ? 1 : v));
        }
        if (i == 0) row_ptr[NN] = EE;
        return;
    }
    if (phase == 5) {
        if (gidx < EE) {
            int is64 = flag[0];
            int d = is64 ? (int)((const long long*)dstp)[gidx] : ((const int*)dstp)[gidx];
            int c = is64 ? (int)((const long long*)srcp)[gidx] : ((const int*)srcp)[gidx];
            if ((unsigned int)d < (unsigned int)NN && (unsigned int)c < (unsigned int)NN) {
                int pos = atomicAdd(&deg[d], 1);
                if ((unsigned int)pos < (unsigned int)EE) col_idx[pos] = c;
            }
        }
        return;
    }
    if (phase == 6) {
        // thread = (node v, slot d in [0,32)); pad slots written as 0
        int v = gidx >> 5;
        int d = gidx & 31;
        if (v < NN) {
            unsigned short val = 0;
            if (d < CF) {
                float x = feat_at(featp, (long long)v * DD + chunk * CF + d, flag[1]);
                val = bf16_st(x * norm[v]);
            }
            gout[(long long)v * PS + d] = val;
        }
        return;
    }
    // phase 7: gather-propagate on one 64-B-row chunk plane.
    // Wave = one node. lane -> (group g = lane>>3, slot s = lane&7).
    // Each wave-instruction gathers 8 rows (8 B/lane, dwordx2); per-slot
    // accumulators, butterfly reduce over groups at the end.
    {
        const int lane = tid & 63;
        const int g = lane >> 3;
        const int s = lane & 7;
        const int v = (blockIdx.x << 2) + (tid >> 6);
        if (v >= NN) return;
        const int beg = row_ptr[v];
        const int end = row_ptr[v + 1];
        float a0 = 0.0f, a1 = 0.0f, a2 = 0.0f, a3 = 0.0f;
        for (int base = beg; base < end; base += 64) {
            int idx = base + lane;
            int my = (idx < end) ? __builtin_nontemporal_load(col_idx + idx) : 0;
            int cnt = end - base;
            if (cnt > 64) cnt = 64;
            for (int j = 0; j < cnt; j += 16) {
                int ja = j + g, jb = j + 8 + g;
                int ca = __shfl(my, ja, 64);
                int cb = __shfl(my, jb, 64);
                if (ja >= cnt) ca = 0;
                if (jb >= cnt) cb = 0;
                uint2 wa = *reinterpret_cast<const uint2*>(gin + (long long)ca * PS + s * 4);
                uint2 wb = *reinterpret_cast<const uint2*>(gin + (long long)cb * PS + s * 4);
                if (ja >= cnt) { wa.x = 0u; wa.y = 0u; }
                if (jb >= cnt) { wb.x = 0u; wb.y = 0u; }
                a0 += __uint_as_float(wa.x << 16);
                a1 += __uint_as_float(wa.x & 0xffff0000u);
                a2 += __uint_as_float(wa.y << 16);
                a3 += __uint_as_float(wa.y & 0xffff0000u);
                a0 += __uint_as_float(wb.x << 16);
                a1 += __uint_as_float(wb.x & 0xffff0000u);
                a2 += __uint_as_float(wb.y << 16);
                a3 += __uint_as_float(wb.y & 0xffff0000u);
            }
        }
        // reduce over the 8 groups (lane bits 3,4,5)
        a0 += __shfl_xor(a0, 8, 64);  a1 += __shfl_xor(a1, 8, 64);
        a2 += __shfl_xor(a2, 8, 64);  a3 += __shfl_xor(a3, 8, 64);
        a0 += __shfl_xor(a0, 16, 64); a1 += __shfl_xor(a1, 16, 64);
        a2 += __shfl_xor(a2, 16, 64); a3 += __shfl_xor(a3, 16, 64);
        a0 += __shfl_xor(a0, 32, 64); a1 += __shfl_xor(a1, 32, 64);
        a2 += __shfl_xor(a2, 32, 64); a3 += __shfl_xor(a3, 32, 64);
        if (g == 0) {
            const float nv = norm[v];
            const int ft = flag[1];
            float acc[4] = {a0, a1, a2, a3};
            if (last) {
                #pragma unroll
                for (int k = 0; k < 4; ++k) {
                    int e = s * 4 + k;
                    if (e < CF) {
                        long long fi = (long long)v * DD + chunk * CF + e;
                        float f0 = feat_nt(featp, fi, ft);
                        outp[fi] = 0.9f * (acc[k] * nv) + 0.1f * f0;
                    }
                }
            } else {
                unsigned short h[4];
                #pragma unroll
                for (int k = 0; k < 4; ++k) {
                    int e = s * 4 + k;
                    if (e < CF) {
                        long long fi = (long long)v * DD + chunk * CF + e;
                        float f0 = feat_nt(featp, fi, ft);
                        float res = 0.9f * (acc[k] * nv) + 0.1f * f0;
                        h[k] = bf16_st(res * nv);
                    } else {
                        h[k] = 0;
                    }
                }
                unsigned long long pk =
                    (unsigned long long)h[0]
                    | ((unsigned long long)h[1] << 16)
                    | ((unsigned long long)h[2] << 32)
                    | ((unsigned long long)h[3] << 48);
                __builtin_nontemporal_store(pk,
                    reinterpret_cast<unsigned long long*>(gout + (long long)v * PS + s * 4));
            }
        }
    }
}

extern "C" void kernel_launch(void* const* d_in, const int* in_sizes, int n_in,
                              void* d_out, int out_size, void* d_ws, size_t ws_size,
                              hipStream_t stream) {
    const void* featp = d_in[0];
    const void* src = d_in[1];
    const void* dst = d_in[2];
    float* outf = (float*)d_out;
    size_t out_bytes = (size_t)out_size * 4;
    (void)in_sizes;

    if (n_in != 3) {
        hipMemsetAsync(d_out, 0x50, out_bytes, stream);
        return;
    }

    size_t a_deg  = (((size_t)NN * 4) + 255) / 256 * 256;
    size_t a_norm = a_deg;
    size_t a_rp   = (((size_t)(NN + 1) * 4) + 255) / 256 * 256;
    size_t a_col  = (((size_t)EE * 4) + 255) / 256 * 256;
    size_t a_bsum = (((size_t)NBLK * 4) + 255) / 256 * 256;
    size_t a_flag = 256;
    size_t a_buf  = (((size_t)NN * PS * 2) + 255) / 256 * 256; // 6.4 MB per plane
    if (ws_size < a_deg + a_norm + a_rp + a_col + a_bsum + a_flag + 2 * a_buf) {
        hipMemsetAsync(d_out, 0x40, out_bytes, stream);
        return;
    }
    char* p = (char*)d_ws;
    int* deg      = (int*)p;   p += a_deg;
    float* norm   = (float*)p; p += a_norm;
    int* row_ptr  = (int*)p;   p += a_rp;
    int* col_idx  = (int*)p;   p += a_col;
    int* bsum     = (int*)p;   p += a_bsum;
    int* flag     = (int*)p;   p += a_flag;
    unsigned short* P0 = (unsigned short*)p; p += a_buf;
    unsigned short* P1 = (unsigned short*)p;

    (void)hipGetLastError();

    #define LCH(grid, blk, gi, go, ph, la, ch) \
        APPNPConv_62199716381208_kernel<<<(grid), (blk), 0, stream>>>( \
            featp, src, dst, deg, norm, row_ptr, col_idx, bsum, flag, \
            (gi), (go), outf, (ph), (la), (ch))

    LCH(NBLK, 256, P0, P0, 0, 0, 0);                 // zero deg + probes
    LCH((EE + 255) / 256, 256, P0, P0, 1, 0, 0);     // indeg (atomics)
    LCH(NBLK, 256, P0, P0, 2, 0, 0);                 // chunk sums
    LCH(1, 512, P0, P0, 3, 0, 0);                    // scan
    LCH(NBLK, 256, P0, P0, 4, 0, 0);                 // rowptr + cursor + norm
    LCH((EE + 255) / 256, 256, P0, P0, 5, 0, 0);     // scatter col_idx

    // Two sequential feature chunks; planes ping-pong entirely inside ws.
    for (int c = 0; c < 2; ++c) {
        LCH((NN * PS) / 256, 256, P0, P0, 6, 0, c);  // g0 -> P0 (zero-padded)
        for (int it = 1; it <= KK; ++it) {
            const unsigned short* gi = (it & 1) ? P0 : P1;
            unsigned short* go       = (it & 1) ? P1 : P0;
            LCH(NN / 4, 256, gi, go, 7, (it == KK) ? 1 : 0, c);
        }
    }
    #undef LCH

    if (hipGetLastError() != hipSuccess) {
        hipMemsetAsync(d_out, 0xBF, out_bytes, stream);
    }
}

// Round 2
// 724.880 us; speedup vs baseline: 2.1122x; 2.1122x over previous
//
#include <hip/hip_runtime.h>

// APPNP propagation - ROUND 16: atomic-free CSC build + revert gather to R14.
// R15 post-mortem: feature-chunked 64-B rows gave ZERO per-iteration gain
// (62 us vs 52 us) -> gather cost is edge-count bound at ~60 Glines/s
// scattered-read rate, independent of plane size. Reverted phases 6/7 to the
// proven 128-B-row broadcast gather (10 iters, ~52 us each).
// New target: phases 1+5 (2 x 130 us, WRITE 105.8 MB = 1.6M x 64 B) are
// device-atomic bound: every global atomic = one 64-B memory-side writeback,
// ~12.3 G atomics/s. Replace with a counting sort using ONLY LDS atomics:
//   phA: (32 slices x 8 ranges) blocks histogram 50k-edge slice for a
//        12.5k-node range in 50 KB LDS -> counts[s][node] (coalesced store;
//        12.8 MB table lives in d_out, dead until phase 6).
//   phB1: deg[n] = sum_s counts[s][n]; norm; block sums.  phB2: scan.
//   phB3: row_ptr via LDS scan; counts[s][n] rewritten in-place to exclusive
//        base offsets (row_ptr[n] + prefix over slices).
//   phC: blocks reload base row into LDS cursors, re-stream slice, LDS
//        atomicAdd -> unique position -> plain col_idx store.
// Build kernel is a separate __global__ so its 50 KB LDS does not cap
// phase-7 occupancy.
//
// Math: feat_{k+1} = 0.9 * norm * (A_T (feat_k * norm)) + 0.1 * feat_0,
// norm = clip(indeg,1)^(-0.5), indeg over dst (d_in[1]=src, d_in[2]=dst).
//
// Buffers: g stored bf16 at stride GS=64 (12.8 MB). d_out doubles as scratch:
// counts table during build, then bf16 plane: g0 -> d_out; odd its
// d_out -> bufA(ws); even its bufA -> d_out; it10 (even) reads bufA, writes
// FINAL fp32 (stride 50) into d_out.

#define NN 100000
#define EE 1600000
#define DD 50
#define GS 64
#define KK 10
#define NBLK 391
#define SLICES 32
#define RANGES 8
#define NR (NN / RANGES)   // 12500 nodes per range
#define ES (EE / SLICES)   // 50000 edges per slice

__device__ __forceinline__ float feat_at(const void* f, long long i, int ft) {
    if (ft) return ((const float*)f)[i];
    unsigned int w = ((unsigned int)((const unsigned short*)f)[i]) << 16;
    return __uint_as_float(w);
}

__device__ __forceinline__ float bf16_ld(const unsigned short* p, int i) {
    unsigned int w = ((unsigned int)p[i]) << 16;
    return __uint_as_float(w);
}

__device__ __forceinline__ unsigned short bf16_st(float x) {
    unsigned int u = __float_as_uint(x);
    unsigned int r = (u + 0x7FFF + ((u >> 16) & 1)) >> 16; // round-nearest-even
    return (unsigned short)r;
}

// ---- build kernel: LDS-histogram count (phase 0) / scatter (phase 1) ----
__global__ __launch_bounds__(512) void APPNPConv_62199716381208_build(
        const void* srcp, const void* dstp, unsigned int* counts,
        int* col_idx, const int* flag, int phase) {
    __shared__ unsigned int hist[NR]; // 50 KB
    const int tid = threadIdx.x;
    const int r = blockIdx.x / SLICES;
    const int s = blockIdx.x % SLICES;
    const int r0 = r * NR;
    const int is64 = flag[0];
    const int e0 = s * ES;

    if (phase == 0) {
        for (int i = tid; i < NR; i += 512) hist[i] = 0u;
        __syncthreads();
        for (int i = tid; i < ES; i += 512) {
            int e = e0 + i;
            int d = is64 ? (int)((const long long*)dstp)[e]
                         : ((const int*)dstp)[e];
            unsigned int dr = (unsigned int)(d - r0);
            if (dr < (unsigned int)NR) atomicAdd(&hist[dr], 1u);
        }
        __syncthreads();
        for (int i = tid; i < NR; i += 512)
            counts[(size_t)s * NN + r0 + i] = hist[i];
    } else {
        for (int i = tid; i < NR; i += 512)
            hist[i] = counts[(size_t)s * NN + r0 + i];
        __syncthreads();
        for (int i = tid; i < ES; i += 512) {
            int e = e0 + i;
            int d = is64 ? (int)((const long long*)dstp)[e]
                         : ((const int*)dstp)[e];
            int c = is64 ? (int)((const long long*)srcp)[e]
                         : ((const int*)srcp)[e];
            unsigned int dr = (unsigned int)(d - r0);
            if (dr < (unsigned int)NR) {
                unsigned int pos = atomicAdd(&hist[dr], 1u);
                if (pos < (unsigned int)EE)
                    col_idx[pos] = ((unsigned int)c < (unsigned int)NN) ? c : 0;
            }
        }
    }
}

// ---- main kernel ----
// Phases: 0 probes | 2 totals+chunk sums+norm | 3 scan | 4 rowptr+base |
// 6 g0 | 7 gather-propagate (round-14 form).
__global__ __launch_bounds__(512) void APPNPConv_62199716381208_kernel(
        const void* featp, const void* srcp, const void* dstp,
        int* deg, float* norm, int* row_ptr, int* col_idx, int* bsum, int* flag,
        unsigned int* counts,
        const unsigned short* gin, unsigned short* gout, float* outp,
        int phase, int last) {
    __shared__ int sh[512];
    const int tid = threadIdx.x;

    if (phase == 0) {
        if (blockIdx.x == 0 && tid == 0) {
            const int* a = (const int*)dstp;
            int odd_or = a[1] | a[3] | a[5] | a[7] | a[9] | a[11] | a[13] | a[15];
            flag[0] = (odd_or == 0) ? 1 : 0;
            const unsigned short* w = (const unsigned short*)featp;
            int isf32 = 0;
            for (int k = 0; k < 64; ++k) {
                unsigned int b = ((unsigned int)w[k]) << 16;
                float ax = fabsf(__uint_as_float(b));
                if (!(ax < 100.0f)) isf32 = 1;
            }
            flag[1] = isf32;
        }
        return;
    }
    if (phase == 2) {
        // per-node totals over slices + chunk sums + norm + deg
        int n = blockIdx.x * 256 + tid;
        int total = 0;
        if (n < NN) {
            #pragma unroll 4
            for (int s = 0; s < SLICES; ++s)
                total += (int)counts[(size_t)s * NN + n];
            deg[n] = total;
            norm[n] = rsqrtf((float)(total < 1 ? 1 : total));
        }
        sh[tid] = total;
        __syncthreads();
        for (int off = 128; off > 0; off >>= 1) {
            if (tid < off) sh[tid] += sh[tid + off];
            __syncthreads();
        }
        if (tid == 0) bsum[blockIdx.x] = sh[0];
        return;
    }
    if (phase == 3) {
        int v = (tid < NBLK) ? bsum[tid] : 0;
        sh[tid] = v;
        __syncthreads();
        for (int off = 1; off < 512; off <<= 1) {
            int x = (tid >= off) ? sh[tid - off] : 0;
            __syncthreads();
            sh[tid] += x;
            __syncthreads();
        }
        if (tid < NBLK) bsum[tid] = sh[tid] - v;
        return;
    }
    if (phase == 4) {
        // row_ptr via LDS scan, then rewrite counts -> exclusive slice bases
        int i = blockIdx.x * 256 + tid;
        int v = (i < NN) ? deg[i] : 0;
        sh[tid] = v;
        __syncthreads();
        for (int off = 1; off < 256; off <<= 1) {
            int x = (tid >= off) ? sh[tid - off] : 0;
            __syncthreads();
            sh[tid] += x;
            __syncthreads();
        }
        int excl = sh[tid] - v + bsum[blockIdx.x];
        if (i < NN) {
            row_ptr[i] = excl;
            unsigned int run = (unsigned int)excl;
            for (int s = 0; s < SLICES; ++s) {
                size_t o = (size_t)s * NN + i;
                unsigned int c = counts[o];
                counts[o] = run;
                run += c;
            }
        }
        if (i == 0) row_ptr[NN] = EE;
        return;
    }
    if (phase == 6) {
        // thread = (node v, slot d) with d in [0,64); write only d < 50
        int gidx = blockIdx.x * 256 + tid;
        int v = gidx >> 6;
        int d = gidx & 63;
        if (v < NN && d < DD) {
            float x = feat_at(featp, (long long)v * DD + d, flag[1]);
            gout[v * GS + d] = bf16_st(x * norm[v]);
        }
        return;
    }
    // phase 7: gather-propagate. One wave per node, lane = feature.
    // 64-index coalesced preload + shfl broadcast; 8 loads in flight.
    {
        const int lane = tid & 63;
        const int v = (blockIdx.x << 2) + (tid >> 6);
        if (v >= NN) return;
        const int beg = row_ptr[v];
        const int end = row_ptr[v + 1];
        float s0 = 0.0f, s1 = 0.0f, s2 = 0.0f, s3 = 0.0f;
        for (int base = beg; base < end; base += 64) {
            int idx = base + lane;
            int my = (idx < end) ? col_idx[idx] : 0;
            int cnt = end - base;
            if (cnt > 64) cnt = 64;
            int j = 0;
            for (; j + 8 <= cnt; j += 8) {
                int c0 = __shfl(my, j, 64);
                int c1 = __shfl(my, j + 1, 64);
                int c2 = __shfl(my, j + 2, 64);
                int c3 = __shfl(my, j + 3, 64);
                int c4 = __shfl(my, j + 4, 64);
                int c5 = __shfl(my, j + 5, 64);
                int c6 = __shfl(my, j + 6, 64);
                int c7 = __shfl(my, j + 7, 64);
                if (lane < DD) {
                    float v0 = bf16_ld(gin, c0 * GS + lane);
                    float v1 = bf16_ld(gin, c1 * GS + lane);
                    float v2 = bf16_ld(gin, c2 * GS + lane);
                    float v3 = bf16_ld(gin, c3 * GS + lane);
                    float v4 = bf16_ld(gin, c4 * GS + lane);
                    float v5 = bf16_ld(gin, c5 * GS + lane);
                    float v6 = bf16_ld(gin, c6 * GS + lane);
                    float v7 = bf16_ld(gin, c7 * GS + lane);
                    s0 += v0 + v4;
                    s1 += v1 + v5;
                    s2 += v2 + v6;
                    s3 += v3 + v7;
                }
            }
            for (; j + 4 <= cnt; j += 4) {
                int c0 = __shfl(my, j, 64);
                int c1 = __shfl(my, j + 1, 64);
                int c2 = __shfl(my, j + 2, 64);
                int c3 = __shfl(my, j + 3, 64);
                if (lane < DD) {
                    s0 += bf16_ld(gin, c0 * GS + lane);
                    s1 += bf16_ld(gin, c1 * GS + lane);
                    s2 += bf16_ld(gin, c2 * GS + lane);
                    s3 += bf16_ld(gin, c3 * GS + lane);
                }
            }
            for (; j < cnt; ++j) {
                int c = __shfl(my, j, 64);
                if (lane < DD) s0 += bf16_ld(gin, c * GS + lane);
            }
        }
        if (lane < DD) {
            float sum = (s0 + s1) + (s2 + s3);
            float nv = norm[v];
            float f0 = feat_at(featp, (long long)v * DD + lane, flag[1]);
            float res = 0.9f * (sum * nv) + 0.1f * f0;
            if (last) outp[v * DD + lane] = res;
            else      gout[v * GS + lane] = bf16_st(res * nv);
        }
    }
}

extern "C" void kernel_launch(void* const* d_in, const int* in_sizes, int n_in,
                              void* d_out, int out_size, void* d_ws, size_t ws_size,
                              hipStream_t stream) {
    const void* featp = d_in[0];
    const void* src = d_in[1];
    const void* dst = d_in[2];
    float* outf = (float*)d_out;
    unsigned short* outb16 = (unsigned short*)d_out; // bf16 scratch plane
    unsigned int* counts = (unsigned int*)d_out;     // 12.8 MB counts table (build only)
    size_t out_bytes = (size_t)out_size * 4;
    (void)in_sizes;

    if (n_in != 3) {
        hipMemsetAsync(d_out, 0x50, out_bytes, stream);
        return;
    }

    size_t a_deg  = (((size_t)NN * 4) + 255) / 256 * 256;
    size_t a_norm = a_deg;
    size_t a_rp   = (((size_t)(NN + 1) * 4) + 255) / 256 * 256;
    size_t a_col  = (((size_t)EE * 4) + 255) / 256 * 256;
    size_t a_bsum = (((size_t)NBLK * 4) + 255) / 256 * 256;
    size_t a_flag = 256;
    size_t a_buf  = (((size_t)NN * GS * 2) + 255) / 256 * 256; // 12.8 MB padded bf16
    if (ws_size < a_deg + a_norm + a_rp + a_col + a_bsum + a_flag + a_buf ||
        out_bytes < (size_t)SLICES * NN * 4) {
        hipMemsetAsync(d_out, 0x40, out_bytes, stream);
        return;
    }
    char* p = (char*)d_ws;
    int* deg      = (int*)p;   p += a_deg;
    float* norm   = (float*)p; p += a_norm;
    int* row_ptr  = (int*)p;   p += a_rp;
    int* col_idx  = (int*)p;   p += a_col;
    int* bsum     = (int*)p;   p += a_bsum;
    int* flag     = (int*)p;   p += a_flag;
    unsigned short* bufA = (unsigned short*)p;

    (void)hipGetLastError();

    #define LCH(grid, blk, gi, go, ph, la) \
        APPNPConv_62199716381208_kernel<<<(grid), (blk), 0, stream>>>( \
            featp, src, dst, deg, norm, row_ptr, col_idx, bsum, flag, counts, \
            (gi), (go), outf, (ph), (la))
    #define LCB(ph) \
        APPNPConv_62199716381208_build<<<SLICES * RANGES, 512, 0, stream>>>( \
            src, dst, counts, col_idx, flag, (ph))

    LCH(1, 256, bufA, bufA, 0, 0);                    // probes
    LCB(0);                                           // phA: LDS-hist counts
    LCH(NBLK, 256, bufA, bufA, 2, 0);                 // totals + chunk sums + norm
    LCH(1, 512, bufA, bufA, 3, 0);                    // scan
    LCH(NBLK, 256, bufA, bufA, 4, 0);                 // row_ptr + slice bases
    LCB(1);                                           // phC: LDS-cursor scatter
    LCH((NN * GS + 255) / 256, 256, bufA, outb16, 6, 0); // g0 -> d_out (padded)

    // it odd: d_out(bf16) -> bufA ; it even: bufA -> d_out(bf16).
    // it10 (even): gin = bufA (ws), writes FINAL fp32 into d_out. No overlap.
    for (int it = 1; it <= KK; ++it) {
        const unsigned short* gi = (it & 1) ? outb16 : bufA;
        unsigned short* go       = (it & 1) ? bufA : outb16;
        LCH(NN / 4, 256, gi, go, 7, (it == KK) ? 1 : 0);
    }
    #undef LCH
    #undef LCB

    if (hipGetLastError() != hipSuccess) {
        hipMemsetAsync(d_out, 0xBF, out_bytes, stream);
    }
}

// Round 3
// 718.564 us; speedup vs baseline: 2.1307x; 1.0088x over previous
//
#include <hip/hip_runtime.h>

// APPNP propagation - ROUND 17.
// R16 post-mortem: build-phC (scatter) = 95 us with WRITE 59.9 MB vs 6.4 MB
// ideal: col_idx lines are written by 32 slice-blocks spread over 8
// NON-COHERENT XCD L2s -> repeated partial-line memory-side writebacks.
// Fix 1: XCD-aligned range assignment (r = blockIdx%8; dispatch round-robins
// XCDs) so all writers of a line share one L2 -> writes merge.
// Fix 2: build streams edges via longlong2 (2 edges / 16-B load).
// Gather model (fits R14 52us/iter@2-line rows AND R15 62us/iter@1-line rows):
// time ~ scattered row-REQUESTS (1.6M/iter @ ~30G/s), not lines, not hit rate.
// Fix 3: 2 edges per gather instruction: lanes 0-24 load uint (2 bf16) from
// edge j's row, lanes 32-56 from edge j+1; final shfl_xor(32) merges halves.
// VMEM instrs and shfls per edge halve.
//
// Math: feat_{k+1} = 0.9 * norm * (A_T (feat_k * norm)) + 0.1 * feat_0,
// norm = clip(indeg,1)^(-0.5), indeg over dst (d_in[1]=src, d_in[2]=dst).
//
// Buffers: counts table (12.8 MB) in d_out during build; then bf16 plane
// (stride GS=64, 12.8 MB): g0 -> d_out; odd its d_out -> bufA(ws); even its
// bufA -> d_out; it10 (even) reads bufA, writes FINAL fp32 into d_out.
//
// Phases: 0 probes | A count | 2 totals+norm | 3 scan | 4 rowptr+slice bases
// | C scatter | 6 g0 | 7 gather-propagate.

#define NN 100000
#define EE 1600000
#define DD 50
#define GS 64
#define KK 10
#define NBLK 391
#define SLICES 32
#define RANGES 8
#define NR (NN / RANGES)   // 12500 nodes per range
#define ES (EE / SLICES)   // 50000 edges per slice

__device__ __forceinline__ float feat_at(const void* f, long long i, int ft) {
    if (ft) return ((const float*)f)[i];
    unsigned int w = ((unsigned int)((const unsigned short*)f)[i]) << 16;
    return __uint_as_float(w);
}

__device__ __forceinline__ unsigned short bf16_st(float x) {
    unsigned int u = __float_as_uint(x);
    unsigned int r = (u + 0x7FFF + ((u >> 16) & 1)) >> 16; // round-nearest-even
    return (unsigned short)r;
}

// ---- build kernel: LDS-histogram count (phase 0) / scatter (phase 1) ----
__global__ __launch_bounds__(512) void APPNPConv_62199716381208_build(
        const void* srcp, const void* dstp, unsigned int* counts,
        int* col_idx, const int* flag, int phase) {
    __shared__ unsigned int hist[NR]; // 50 KB
    const int tid = threadIdx.x;
    const int r = blockIdx.x & 7;   // XCD-aligned: all slices of range r on one XCD
    const int s = blockIdx.x >> 3;  // slice 0..31
    const int r0 = r * NR;
    const int is64 = flag[0];
    const long long e0 = (long long)s * ES;

    if (phase == 0) {
        for (int i = tid; i < NR; i += 512) hist[i] = 0u;
        __syncthreads();
        if (is64) {
            const longlong2* dp = (const longlong2*)((const long long*)dstp + e0);
            for (int i = tid; i < ES / 2; i += 512) {
                longlong2 dd = dp[i];
                unsigned int a = (unsigned int)((int)dd.x - r0);
                unsigned int b = (unsigned int)((int)dd.y - r0);
                if (a < (unsigned int)NR) atomicAdd(&hist[a], 1u);
                if (b < (unsigned int)NR) atomicAdd(&hist[b], 1u);
            }
        } else {
            const int2* dp = (const int2*)((const int*)dstp + e0);
            for (int i = tid; i < ES / 2; i += 512) {
                int2 dd = dp[i];
                unsigned int a = (unsigned int)(dd.x - r0);
                unsigned int b = (unsigned int)(dd.y - r0);
                if (a < (unsigned int)NR) atomicAdd(&hist[a], 1u);
                if (b < (unsigned int)NR) atomicAdd(&hist[b], 1u);
            }
        }
        __syncthreads();
        for (int i = tid; i < NR; i += 512)
            counts[(size_t)s * NN + r0 + i] = hist[i];
    } else {
        for (int i = tid; i < NR; i += 512)
            hist[i] = counts[(size_t)s * NN + r0 + i];
        __syncthreads();
        if (is64) {
            const longlong2* dp = (const longlong2*)((const long long*)dstp + e0);
            const longlong2* sp = (const longlong2*)((const long long*)srcp + e0);
            for (int i = tid; i < ES / 2; i += 512) {
                longlong2 dd = dp[i];
                longlong2 ss = sp[i];
                unsigned int a = (unsigned int)((int)dd.x - r0);
                unsigned int b = (unsigned int)((int)dd.y - r0);
                if (a < (unsigned int)NR) {
                    unsigned int pos = atomicAdd(&hist[a], 1u);
                    int c = (int)ss.x;
                    if (pos < (unsigned int)EE)
                        col_idx[pos] = ((unsigned int)c < (unsigned int)NN) ? c : 0;
                }
                if (b < (unsigned int)NR) {
                    unsigned int pos = atomicAdd(&hist[b], 1u);
                    int c = (int)ss.y;
                    if (pos < (unsigned int)EE)
                        col_idx[pos] = ((unsigned int)c < (unsigned int)NN) ? c : 0;
                }
            }
        } else {
            const int2* dp = (const int2*)((const int*)dstp + e0);
            const int2* sp = (const int2*)((const int*)srcp + e0);
            for (int i = tid; i < ES / 2; i += 512) {
                int2 dd = dp[i];
                int2 ss = sp[i];
                unsigned int a = (unsigned int)(dd.x - r0);
                unsigned int b = (unsigned int)(dd.y - r0);
                if (a < (unsigned int)NR) {
                    unsigned int pos = atomicAdd(&hist[a], 1u);
                    if (pos < (unsigned int)EE)
                        col_idx[pos] = ((unsigned int)ss.x < (unsigned int)NN) ? ss.x : 0;
                }
                if (b < (unsigned int)NR) {
                    unsigned int pos = atomicAdd(&hist[b], 1u);
                    if (pos < (unsigned int)EE)
                        col_idx[pos] = ((unsigned int)ss.y < (unsigned int)NN) ? ss.y : 0;
                }
            }
        }
    }
}

// ---- main kernel ----
__global__ __launch_bounds__(512) void APPNPConv_62199716381208_kernel(
        const void* featp, const void* srcp, const void* dstp,
        int* deg, float* norm, int* row_ptr, int* col_idx, int* bsum, int* flag,
        unsigned int* counts,
        const unsigned short* gin, unsigned short* gout, float* outp,
        int phase, int last) {
    __shared__ int sh[512];
    const int tid = threadIdx.x;

    if (phase == 0) {
        if (blockIdx.x == 0 && tid == 0) {
            const int* a = (const int*)dstp;
            int odd_or = a[1] | a[3] | a[5] | a[7] | a[9] | a[11] | a[13] | a[15];
            flag[0] = (odd_or == 0) ? 1 : 0;
            const unsigned short* w = (const unsigned short*)featp;
            int isf32 = 0;
            for (int k = 0; k < 64; ++k) {
                unsigned int b = ((unsigned int)w[k]) << 16;
                float ax = fabsf(__uint_as_float(b));
                if (!(ax < 100.0f)) isf32 = 1;
            }
            flag[1] = isf32;
        }
        return;
    }
    if (phase == 2) {
        int n = blockIdx.x * 256 + tid;
        int total = 0;
        if (n < NN) {
            #pragma unroll 4
            for (int s = 0; s < SLICES; ++s)
                total += (int)counts[(size_t)s * NN + n];
            deg[n] = total;
            norm[n] = rsqrtf((float)(total < 1 ? 1 : total));
        }
        sh[tid] = total;
        __syncthreads();
        for (int off = 128; off > 0; off >>= 1) {
            if (tid < off) sh[tid] += sh[tid + off];
            __syncthreads();
        }
        if (tid == 0) bsum[blockIdx.x] = sh[0];
        return;
    }
    if (phase == 3) {
        int v = (tid < NBLK) ? bsum[tid] : 0;
        sh[tid] = v;
        __syncthreads();
        for (int off = 1; off < 512; off <<= 1) {
            int x = (tid >= off) ? sh[tid - off] : 0;
            __syncthreads();
            sh[tid] += x;
            __syncthreads();
        }
        if (tid < NBLK) bsum[tid] = sh[tid] - v;
        return;
    }
    if (phase == 4) {
        int i = blockIdx.x * 256 + tid;
        int v = (i < NN) ? deg[i] : 0;
        sh[tid] = v;
        __syncthreads();
        for (int off = 1; off < 256; off <<= 1) {
            int x = (tid >= off) ? sh[tid - off] : 0;
            __syncthreads();
            sh[tid] += x;
            __syncthreads();
        }
        int excl = sh[tid] - v + bsum[blockIdx.x];
        if (i < NN) {
            row_ptr[i] = excl;
            unsigned int run = (unsigned int)excl;
            for (int s = 0; s < SLICES; ++s) {
                size_t o = (size_t)s * NN + i;
                unsigned int c = counts[o];
                counts[o] = run;
                run += c;
            }
        }
        if (i == 0) row_ptr[NN] = EE;
        return;
    }
    if (phase == 6) {
        int gidx = blockIdx.x * 256 + tid;
        int v = gidx >> 6;
        int d = gidx & 63;
        if (v < NN && d < DD) {
            float x = feat_at(featp, (long long)v * DD + d, flag[1]);
            gout[v * GS + d] = bf16_st(x * norm[v]);
        }
        return;
    }
    // phase 7: gather-propagate, 2 edges per instruction.
    // Wave = one node. half = lane>>5 picks edge j / j+1; l = lane&31 is the
    // uint slot (features 2l, 2l+1), active for l < 25. Final shfl_xor(32)
    // merges even-edge and odd-edge partial sums.
    {
        const int lane = tid & 63;
        const int half = lane >> 5;
        const int l = lane & 31;
        const int v = (blockIdx.x << 2) + (tid >> 6);
        if (v >= NN) return;
        const int beg = row_ptr[v];
        const int end = row_ptr[v + 1];
        const unsigned int* gp = (const unsigned int*)gin;
        const int active = (l < 25);
        float e0 = 0.0f, o0 = 0.0f, e1 = 0.0f, o1 = 0.0f;
        for (int base = beg; base < end; base += 64) {
            int idx = base + lane;
            int my = (idx < end) ? col_idx[idx] : 0;
            int cnt = end - base;
            if (cnt > 64) cnt = 64;
            int j = 0;
            for (; j + 8 <= cnt; j += 8) {
                int cA = __shfl(my, j + half, 64);
                int cB = __shfl(my, j + 2 + half, 64);
                int cC = __shfl(my, j + 4 + half, 64);
                int cD = __shfl(my, j + 6 + half, 64);
                if (active) {
                    unsigned int uA = gp[(cA << 5) + l];
                    unsigned int uB = gp[(cB << 5) + l];
                    unsigned int uC = gp[(cC << 5) + l];
                    unsigned int uD = gp[(cD << 5) + l];
                    e0 += __uint_as_float(uA << 16);
                    o0 += __uint_as_float(uA & 0xffff0000u);
                    e1 += __uint_as_float(uB << 16);
                    o1 += __uint_as_float(uB & 0xffff0000u);
                    e0 += __uint_as_float(uC << 16);
                    o0 += __uint_as_float(uC & 0xffff0000u);
                    e1 += __uint_as_float(uD << 16);
                    o1 += __uint_as_float(uD & 0xffff0000u);
                }
            }
            for (; j < cnt; j += 2) {
                int jj = j + half;
                int c = __shfl(my, (jj < cnt) ? jj : j, 64);
                if (active) {
                    unsigned int u = gp[(c << 5) + l];
                    if (jj >= cnt) u = 0u;
                    e0 += __uint_as_float(u << 16);
                    o0 += __uint_as_float(u & 0xffff0000u);
                }
            }
        }
        float fe = e0 + e1;
        float fo = o0 + o1;
        fe += __shfl_xor(fe, 32, 64);
        fo += __shfl_xor(fo, 32, 64);
        if (half == 0 && active) {
            const float nv = norm[v];
            const int ft = flag[1];
            float f0e, f0o;
            if (ft) {
                float2 f02 = *reinterpret_cast<const float2*>(
                    (const float*)featp + ((long long)v * DD + 2 * l));
                f0e = f02.x; f0o = f02.y;
            } else {
                unsigned int w = ((const unsigned int*)featp)[v * 25 + l];
                f0e = __uint_as_float(w << 16);
                f0o = __uint_as_float(w & 0xffff0000u);
            }
            float rE = 0.9f * (fe * nv) + 0.1f * f0e;
            float rO = 0.9f * (fo * nv) + 0.1f * f0o;
            if (last) {
                float2 st; st.x = rE; st.y = rO;
                *reinterpret_cast<float2*>(outp + ((long long)v * DD + 2 * l)) = st;
            } else {
                unsigned int pk = (unsigned int)bf16_st(rE * nv)
                                | ((unsigned int)bf16_st(rO * nv) << 16);
                ((unsigned int*)gout)[(v << 5) + l] = pk;
            }
        }
    }
}

extern "C" void kernel_launch(void* const* d_in, const int* in_sizes, int n_in,
                              void* d_out, int out_size, void* d_ws, size_t ws_size,
                              hipStream_t stream) {
    const void* featp = d_in[0];
    const void* src = d_in[1];
    const void* dst = d_in[2];
    float* outf = (float*)d_out;
    unsigned short* outb16 = (unsigned short*)d_out; // bf16 scratch plane
    unsigned int* counts = (unsigned int*)d_out;     // 12.8 MB counts (build only)
    size_t out_bytes = (size_t)out_size * 4;
    (void)in_sizes;

    if (n_in != 3) {
        hipMemsetAsync(d_out, 0x50, out_bytes, stream);
        return;
    }

    size_t a_deg  = (((size_t)NN * 4) + 255) / 256 * 256;
    size_t a_norm = a_deg;
    size_t a_rp   = (((size_t)(NN + 1) * 4) + 255) / 256 * 256;
    size_t a_col  = (((size_t)EE * 4) + 255) / 256 * 256;
    size_t a_bsum = (((size_t)NBLK * 4) + 255) / 256 * 256;
    size_t a_flag = 256;
    size_t a_buf  = (((size_t)NN * GS * 2) + 255) / 256 * 256; // 12.8 MB padded bf16
    if (ws_size < a_deg + a_norm + a_rp + a_col + a_bsum + a_flag + a_buf ||
        out_bytes < (size_t)SLICES * NN * 4) {
        hipMemsetAsync(d_out, 0x40, out_bytes, stream);
        return;
    }
    char* p = (char*)d_ws;
    int* deg      = (int*)p;   p += a_deg;
    float* norm   = (float*)p; p += a_norm;
    int* row_ptr  = (int*)p;   p += a_rp;
    int* col_idx  = (int*)p;   p += a_col;
    int* bsum     = (int*)p;   p += a_bsum;
    int* flag     = (int*)p;   p += a_flag;
    unsigned short* bufA = (unsigned short*)p;

    (void)hipGetLastError();

    #define LCH(grid, blk, gi, go, ph, la) \
        APPNPConv_62199716381208_kernel<<<(grid), (blk), 0, stream>>>( \
            featp, src, dst, deg, norm, row_ptr, col_idx, bsum, flag, counts, \
            (gi), (go), outf, (ph), (la))
    #define LCB(ph) \
        APPNPConv_62199716381208_build<<<SLICES * RANGES, 512, 0, stream>>>( \
            src, dst, counts, col_idx, flag, (ph))

    LCH(1, 256, bufA, bufA, 0, 0);                    // probes
    LCB(0);                                           // phA: LDS-hist counts
    LCH(NBLK, 256, bufA, bufA, 2, 0);                 // totals + norm
    LCH(1, 512, bufA, bufA, 3, 0);                    // scan
    LCH(NBLK, 256, bufA, bufA, 4, 0);                 // row_ptr + slice bases
    LCB(1);                                           // phC: LDS-cursor scatter
    LCH((NN * GS + 255) / 256, 256, bufA, outb16, 6, 0); // g0 -> d_out (padded)

    for (int it = 1; it <= KK; ++it) {
        const unsigned short* gi = (it & 1) ? outb16 : bufA;
        unsigned short* go       = (it & 1) ? bufA : outb16;
        LCH(NN / 4, 256, gi, go, 7, (it == KK) ? 1 : 0);
    }
    #undef LCH
    #undef LCB

    if (hipGetLastError() != hipSuccess) {
        hipMemsetAsync(d_out, 0xBF, out_bytes, stream);
    }
}

// Round 4
// 661.200 us; speedup vs baseline: 2.3156x; 1.0868x over previous
//
#include <hip/hip_runtime.h>

// APPNP propagation - ROUND 18: gather MLP push (16 loads in flight).
// R17 post-mortem: 2-edge packing REGRESSED the gather (58 vs ~52 us/iter)
// despite half the VMEM instructions -> not request-rate bound. Counters:
// FETCH 95 MB/iter, VALUBusy 35%, occ 72%. Outstanding-miss arithmetic:
// 1.49M misses x ~700cy / 58us / 2.4GHz = ~1.3 misses in flight per wave ->
// LATENCY-bound. R17's structure allows only 4 loads in flight (R14: 8).
// Fix: revert to 1-row-per-instruction gather (64 lanes x 2B, one row) and
// unroll to 16 independent loads before any dependent add. Same total line
// traffic; 2-4x MLP. Predict 58 -> ~40 us/iter. If it stays >=52 at same
// FETCH, ~1.7 TB/s random-line serving is a true ceiling -> pivot to
// src-range locality next.
//
// Math: feat_{k+1} = 0.9 * norm * (A_T (feat_k * norm)) + 0.1 * feat_0,
// norm = clip(indeg,1)^(-0.5), indeg over dst (d_in[1]=src, d_in[2]=dst).
//
// Build (R16/17, atomic-free): LDS-histogram counting sort, XCD-aligned
// ranges (r = blk&7), longlong2/int2 edge streams. counts table (12.8 MB)
// lives in d_out during build.
// Plane: bf16, stride GS=64 (12.8 MB). g0 -> d_out; odd its d_out -> bufA;
// even its bufA -> d_out; it10 (even) reads bufA, writes FINAL fp32 to d_out.
//
// Phases: 0 probes | A count | 2 totals+norm | 3 scan | 4 rowptr+slice bases
// | C scatter | 6 g0 | 7 gather-propagate.

#define NN 100000
#define EE 1600000
#define DD 50
#define GS 64
#define KK 10
#define NBLK 391
#define SLICES 32
#define RANGES 8
#define NR (NN / RANGES)   // 12500 nodes per range
#define ES (EE / SLICES)   // 50000 edges per slice

__device__ __forceinline__ float feat_at(const void* f, long long i, int ft) {
    if (ft) return ((const float*)f)[i];
    unsigned int w = ((unsigned int)((const unsigned short*)f)[i]) << 16;
    return __uint_as_float(w);
}

__device__ __forceinline__ float bf16_ld(const unsigned short* p, int i) {
    unsigned int w = ((unsigned int)p[i]) << 16;
    return __uint_as_float(w);
}

__device__ __forceinline__ unsigned short bf16_st(float x) {
    unsigned int u = __float_as_uint(x);
    unsigned int r = (u + 0x7FFF + ((u >> 16) & 1)) >> 16; // round-nearest-even
    return (unsigned short)r;
}

// ---- build kernel: LDS-histogram count (phase 0) / scatter (phase 1) ----
__global__ __launch_bounds__(512) void APPNPConv_62199716381208_build(
        const void* srcp, const void* dstp, unsigned int* counts,
        int* col_idx, const int* flag, int phase) {
    __shared__ unsigned int hist[NR]; // 50 KB
    const int tid = threadIdx.x;
    const int r = blockIdx.x & 7;   // XCD-aligned: all slices of range r on one XCD
    const int s = blockIdx.x >> 3;  // slice 0..31
    const int r0 = r * NR;
    const int is64 = flag[0];
    const long long e0 = (long long)s * ES;

    if (phase == 0) {
        for (int i = tid; i < NR; i += 512) hist[i] = 0u;
        __syncthreads();
        if (is64) {
            const longlong2* dp = (const longlong2*)((const long long*)dstp + e0);
            for (int i = tid; i < ES / 2; i += 512) {
                longlong2 dd = dp[i];
                unsigned int a = (unsigned int)((int)dd.x - r0);
                unsigned int b = (unsigned int)((int)dd.y - r0);
                if (a < (unsigned int)NR) atomicAdd(&hist[a], 1u);
                if (b < (unsigned int)NR) atomicAdd(&hist[b], 1u);
            }
        } else {
            const int2* dp = (const int2*)((const int*)dstp + e0);
            for (int i = tid; i < ES / 2; i += 512) {
                int2 dd = dp[i];
                unsigned int a = (unsigned int)(dd.x - r0);
                unsigned int b = (unsigned int)(dd.y - r0);
                if (a < (unsigned int)NR) atomicAdd(&hist[a], 1u);
                if (b < (unsigned int)NR) atomicAdd(&hist[b], 1u);
            }
        }
        __syncthreads();
        for (int i = tid; i < NR; i += 512)
            counts[(size_t)s * NN + r0 + i] = hist[i];
    } else {
        for (int i = tid; i < NR; i += 512)
            hist[i] = counts[(size_t)s * NN + r0 + i];
        __syncthreads();
        if (is64) {
            const longlong2* dp = (const longlong2*)((const long long*)dstp + e0);
            const longlong2* sp = (const longlong2*)((const long long*)srcp + e0);
            for (int i = tid; i < ES / 2; i += 512) {
                longlong2 dd = dp[i];
                longlong2 ss = sp[i];
                unsigned int a = (unsigned int)((int)dd.x - r0);
                unsigned int b = (unsigned int)((int)dd.y - r0);
                if (a < (unsigned int)NR) {
                    unsigned int pos = atomicAdd(&hist[a], 1u);
                    int c = (int)ss.x;
                    if (pos < (unsigned int)EE)
                        col_idx[pos] = ((unsigned int)c < (unsigned int)NN) ? c : 0;
                }
                if (b < (unsigned int)NR) {
                    unsigned int pos = atomicAdd(&hist[b], 1u);
                    int c = (int)ss.y;
                    if (pos < (unsigned int)EE)
                        col_idx[pos] = ((unsigned int)c < (unsigned int)NN) ? c : 0;
                }
            }
        } else {
            const int2* dp = (const int2*)((const int*)dstp + e0);
            const int2* sp = (const int2*)((const int*)srcp + e0);
            for (int i = tid; i < ES / 2; i += 512) {
                int2 dd = dp[i];
                int2 ss = sp[i];
                unsigned int a = (unsigned int)(dd.x - r0);
                unsigned int b = (unsigned int)(dd.y - r0);
                if (a < (unsigned int)NR) {
                    unsigned int pos = atomicAdd(&hist[a], 1u);
                    if (pos < (unsigned int)EE)
                        col_idx[pos] = ((unsigned int)ss.x < (unsigned int)NN) ? ss.x : 0;
                }
                if (b < (unsigned int)NR) {
                    unsigned int pos = atomicAdd(&hist[b], 1u);
                    if (pos < (unsigned int)EE)
                        col_idx[pos] = ((unsigned int)ss.y < (unsigned int)NN) ? ss.y : 0;
                }
            }
        }
    }
}

// ---- main kernel ----
__global__ __launch_bounds__(512) void APPNPConv_62199716381208_kernel(
        const void* featp, const void* srcp, const void* dstp,
        int* deg, float* norm, int* row_ptr, int* col_idx, int* bsum, int* flag,
        unsigned int* counts,
        const unsigned short* gin, unsigned short* gout, float* outp,
        int phase, int last) {
    __shared__ int sh[512];
    const int tid = threadIdx.x;

    if (phase == 0) {
        if (blockIdx.x == 0 && tid == 0) {
            const int* a = (const int*)dstp;
            int odd_or = a[1] | a[3] | a[5] | a[7] | a[9] | a[11] | a[13] | a[15];
            flag[0] = (odd_or == 0) ? 1 : 0;
            const unsigned short* w = (const unsigned short*)featp;
            int isf32 = 0;
            for (int k = 0; k < 64; ++k) {
                unsigned int b = ((unsigned int)w[k]) << 16;
                float ax = fabsf(__uint_as_float(b));
                if (!(ax < 100.0f)) isf32 = 1;
            }
            flag[1] = isf32;
        }
        return;
    }
    if (phase == 2) {
        int n = blockIdx.x * 256 + tid;
        int total = 0;
        if (n < NN) {
            #pragma unroll 4
            for (int s = 0; s < SLICES; ++s)
                total += (int)counts[(size_t)s * NN + n];
            deg[n] = total;
            norm[n] = rsqrtf((float)(total < 1 ? 1 : total));
        }
        sh[tid] = total;
        __syncthreads();
        for (int off = 128; off > 0; off >>= 1) {
            if (tid < off) sh[tid] += sh[tid + off];
            __syncthreads();
        }
        if (tid == 0) bsum[blockIdx.x] = sh[0];
        return;
    }
    if (phase == 3) {
        int v = (tid < NBLK) ? bsum[tid] : 0;
        sh[tid] = v;
        __syncthreads();
        for (int off = 1; off < 512; off <<= 1) {
            int x = (tid >= off) ? sh[tid - off] : 0;
            __syncthreads();
            sh[tid] += x;
            __syncthreads();
        }
        if (tid < NBLK) bsum[tid] = sh[tid] - v;
        return;
    }
    if (phase == 4) {
        int i = blockIdx.x * 256 + tid;
        int v = (i < NN) ? deg[i] : 0;
        sh[tid] = v;
        __syncthreads();
        for (int off = 1; off < 256; off <<= 1) {
            int x = (tid >= off) ? sh[tid - off] : 0;
            __syncthreads();
            sh[tid] += x;
            __syncthreads();
        }
        int excl = sh[tid] - v + bsum[blockIdx.x];
        if (i < NN) {
            row_ptr[i] = excl;
            unsigned int run = (unsigned int)excl;
            for (int s = 0; s < SLICES; ++s) {
                size_t o = (size_t)s * NN + i;
                unsigned int c = counts[o];
                counts[o] = run;
                run += c;
            }
        }
        if (i == 0) row_ptr[NN] = EE;
        return;
    }
    if (phase == 6) {
        int gidx = blockIdx.x * 256 + tid;
        int v = gidx >> 6;
        int d = gidx & 63;
        if (v < NN && d < DD) {
            float x = feat_at(featp, (long long)v * DD + d, flag[1]);
            gout[v * GS + d] = bf16_st(x * norm[v]);
        }
        return;
    }
    // phase 7: gather-propagate. One wave per node, lane = feature.
    // 64-index coalesced preload + shfl broadcast; 16 loads in flight.
    {
        const int lane = tid & 63;
        const int v = (blockIdx.x << 2) + (tid >> 6);
        if (v >= NN) return;
        const int beg = row_ptr[v];
        const int end = row_ptr[v + 1];
        const int act = (lane < DD);
        float s0 = 0.0f, s1 = 0.0f, s2 = 0.0f, s3 = 0.0f;
        for (int base = beg; base < end; base += 64) {
            int idx = base + lane;
            int my = (idx < end) ? col_idx[idx] : 0;
            int cnt = end - base;
            if (cnt > 64) cnt = 64;
            int j = 0;
            for (; j + 16 <= cnt; j += 16) {
                int c0  = __shfl(my, j,      64);
                int c1  = __shfl(my, j + 1,  64);
                int c2  = __shfl(my, j + 2,  64);
                int c3  = __shfl(my, j + 3,  64);
                int c4  = __shfl(my, j + 4,  64);
                int c5  = __shfl(my, j + 5,  64);
                int c6  = __shfl(my, j + 6,  64);
                int c7  = __shfl(my, j + 7,  64);
                int c8  = __shfl(my, j + 8,  64);
                int c9  = __shfl(my, j + 9,  64);
                int c10 = __shfl(my, j + 10, 64);
                int c11 = __shfl(my, j + 11, 64);
                int c12 = __shfl(my, j + 12, 64);
                int c13 = __shfl(my, j + 13, 64);
                int c14 = __shfl(my, j + 14, 64);
                int c15 = __shfl(my, j + 15, 64);
                if (act) {
                    float v0  = bf16_ld(gin, c0  * GS + lane);
                    float v1  = bf16_ld(gin, c1  * GS + lane);
                    float v2  = bf16_ld(gin, c2  * GS + lane);
                    float v3  = bf16_ld(gin, c3  * GS + lane);
                    float v4  = bf16_ld(gin, c4  * GS + lane);
                    float v5  = bf16_ld(gin, c5  * GS + lane);
                    float v6  = bf16_ld(gin, c6  * GS + lane);
                    float v7  = bf16_ld(gin, c7  * GS + lane);
                    float v8  = bf16_ld(gin, c8  * GS + lane);
                    float v9  = bf16_ld(gin, c9  * GS + lane);
                    float v10 = bf16_ld(gin, c10 * GS + lane);
                    float v11 = bf16_ld(gin, c11 * GS + lane);
                    float v12 = bf16_ld(gin, c12 * GS + lane);
                    float v13 = bf16_ld(gin, c13 * GS + lane);
                    float v14 = bf16_ld(gin, c14 * GS + lane);
                    float v15 = bf16_ld(gin, c15 * GS + lane);
                    s0 += (v0 + v4) + (v8 + v12);
                    s1 += (v1 + v5) + (v9 + v13);
                    s2 += (v2 + v6) + (v10 + v14);
                    s3 += (v3 + v7) + (v11 + v15);
                }
            }
            for (; j + 8 <= cnt; j += 8) {
                int c0 = __shfl(my, j, 64);
                int c1 = __shfl(my, j + 1, 64);
                int c2 = __shfl(my, j + 2, 64);
                int c3 = __shfl(my, j + 3, 64);
                int c4 = __shfl(my, j + 4, 64);
                int c5 = __shfl(my, j + 5, 64);
                int c6 = __shfl(my, j + 6, 64);
                int c7 = __shfl(my, j + 7, 64);
                if (act) {
                    float v0 = bf16_ld(gin, c0 * GS + lane);
                    float v1 = bf16_ld(gin, c1 * GS + lane);
                    float v2 = bf16_ld(gin, c2 * GS + lane);
                    float v3 = bf16_ld(gin, c3 * GS + lane);
                    float v4 = bf16_ld(gin, c4 * GS + lane);
                    float v5 = bf16_ld(gin, c5 * GS + lane);
                    float v6 = bf16_ld(gin, c6 * GS + lane);
                    float v7 = bf16_ld(gin, c7 * GS + lane);
                    s0 += v0 + v4;
                    s1 += v1 + v5;
                    s2 += v2 + v6;
                    s3 += v3 + v7;
                }
            }
            for (; j + 4 <= cnt; j += 4) {
                int c0 = __shfl(my, j, 64);
                int c1 = __shfl(my, j + 1, 64);
                int c2 = __shfl(my, j + 2, 64);
                int c3 = __shfl(my, j + 3, 64);
                if (act) {
                    s0 += bf16_ld(gin, c0 * GS + lane);
                    s1 += bf16_ld(gin, c1 * GS + lane);
                    s2 += bf16_ld(gin, c2 * GS + lane);
                    s3 += bf16_ld(gin, c3 * GS + lane);
                }
            }
            for (; j < cnt; ++j) {
                int c = __shfl(my, j, 64);
                if (act) s0 += bf16_ld(gin, c * GS + lane);
            }
        }
        if (act) {
            float sum = (s0 + s1) + (s2 + s3);
            float nv = norm[v];
            float f0 = feat_at(featp, (long long)v * DD + lane, flag[1]);
            float res = 0.9f * (sum * nv) + 0.1f * f0;
            if (last) outp[v * DD + lane] = res;
            else      gout[v * GS + lane] = bf16_st(res * nv);
        }
    }
}

extern "C" void kernel_launch(void* const* d_in, const int* in_sizes, int n_in,
                              void* d_out, int out_size, void* d_ws, size_t ws_size,
                              hipStream_t stream) {
    const void* featp = d_in[0];
    const void* src = d_in[1];
    const void* dst = d_in[2];
    float* outf = (float*)d_out;
    unsigned short* outb16 = (unsigned short*)d_out; // bf16 scratch plane
    unsigned int* counts = (unsigned int*)d_out;     // 12.8 MB counts (build only)
    size_t out_bytes = (size_t)out_size * 4;
    (void)in_sizes;

    if (n_in != 3) {
        hipMemsetAsync(d_out, 0x50, out_bytes, stream);
        return;
    }

    size_t a_deg  = (((size_t)NN * 4) + 255) / 256 * 256;
    size_t a_norm = a_deg;
    size_t a_rp   = (((size_t)(NN + 1) * 4) + 255) / 256 * 256;
    size_t a_col  = (((size_t)EE * 4) + 255) / 256 * 256;
    size_t a_bsum = (((size_t)NBLK * 4) + 255) / 256 * 256;
    size_t a_flag = 256;
    size_t a_buf  = (((size_t)NN * GS * 2) + 255) / 256 * 256; // 12.8 MB padded bf16
    if (ws_size < a_deg + a_norm + a_rp + a_col + a_bsum + a_flag + a_buf ||
        out_bytes < (size_t)SLICES * NN * 4) {
        hipMemsetAsync(d_out, 0x40, out_bytes, stream);
        return;
    }
    char* p = (char*)d_ws;
    int* deg      = (int*)p;   p += a_deg;
    float* norm   = (float*)p; p += a_norm;
    int* row_ptr  = (int*)p;   p += a_rp;
    int* col_idx  = (int*)p;   p += a_col;
    int* bsum     = (int*)p;   p += a_bsum;
    int* flag     = (int*)p;   p += a_flag;
    unsigned short* bufA = (unsigned short*)p;

    (void)hipGetLastError();

    #define LCH(grid, blk, gi, go, ph, la) \
        APPNPConv_62199716381208_kernel<<<(grid), (blk), 0, stream>>>( \
            featp, src, dst, deg, norm, row_ptr, col_idx, bsum, flag, counts, \
            (gi), (go), outf, (ph), (la))
    #define LCB(ph) \
        APPNPConv_62199716381208_build<<<SLICES * RANGES, 512, 0, stream>>>( \
            src, dst, counts, col_idx, flag, (ph))

    LCH(1, 256, bufA, bufA, 0, 0);                    // probes
    LCB(0);                                           // phA: LDS-hist counts
    LCH(NBLK, 256, bufA, bufA, 2, 0);                 // totals + norm
    LCH(1, 512, bufA, bufA, 3, 0);                    // scan
    LCH(NBLK, 256, bufA, bufA, 4, 0);                 // row_ptr + slice bases
    LCB(1);                                           // phC: LDS-cursor scatter
    LCH((NN * GS + 255) / 256, 256, bufA, outb16, 6, 0); // g0 -> d_out (padded)

    for (int it = 1; it <= KK; ++it) {
        const unsigned short* gi = (it & 1) ? outb16 : bufA;
        unsigned short* go       = (it & 1) ? bufA : outb16;
        LCH(NN / 4, 256, gi, go, 7, (it == KK) ? 1 : 0);
    }
    #undef LCH
    #undef LCB

    if (hipGetLastError() != hipSuccess) {
        hipMemsetAsync(d_out, 0xBF, out_bytes, stream);
    }
}